// Round 15
// baseline (215.078 us; speedup 1.0000x reference)
//
#include <hip/hip_runtime.h>
#include <hip/hip_bf16.h>
#include <hip/hip_fp16.h>

#define EMBED 128
#define HEADS 8
#define DH 16
#define FFN 512
#define BB 16
#define NN 256

typedef float floatx4 __attribute__((ext_vector_type(4)));

// ---- Kernel A: LN1 + QKV, 8 rows/block (weights read once per 8 rows) -----
__global__ __launch_bounds__(128) void ln1_qkv_kernel(
    const float* __restrict__ x,
    const float* __restrict__ ln1_g, const float* __restrict__ ln1_b,
    const float* __restrict__ Wq, const float* __restrict__ bq,
    const float* __restrict__ Wk, const float* __restrict__ bk,
    const float* __restrict__ Wv, const float* __restrict__ bv,
    float* __restrict__ q, float* __restrict__ k, float* __restrict__ v)
{
    const int row0 = blockIdx.x * 8;     // 512 blocks
    const int t    = threadIdx.x;        // 0..127
    const int wv_  = t >> 6;             // wave 0..1
    const int l64  = t & 63;

    __shared__ float xn[8][EMBED];

    #pragma unroll
    for (int rr = 0; rr < 4; ++rr) {
        const int r = wv_ * 4 + rr;
        const float v0 = x[(size_t)(row0 + r) * EMBED + l64];
        const float v1 = x[(size_t)(row0 + r) * EMBED + 64 + l64];
        float s  = v0 + v1;
        float sq = v0 * v0 + v1 * v1;
        #pragma unroll
        for (int off = 32; off >= 1; off >>= 1) {
            s  += __shfl_xor(s, off);
            sq += __shfl_xor(sq, off);
        }
        const float mu  = s * (1.0f / EMBED);
        const float var = sq * (1.0f / EMBED) - mu * mu;
        const float rs  = rsqrtf(var + 1e-5f);
        xn[r][l64]      = (v0 - mu) * rs * ln1_g[l64]      + ln1_b[l64];
        xn[r][l64 + 64] = (v1 - mu) * rs * ln1_g[l64 + 64] + ln1_b[l64 + 64];
    }
    __syncthreads();

    const int e = t;
    float aq[8], ak[8], av[8];
    const float bqe = bq[e], bke = bk[e], bve = bv[e];
    #pragma unroll
    for (int r = 0; r < 8; ++r) { aq[r] = bqe; ak[r] = bke; av[r] = bve; }

    #pragma unroll 4
    for (int c = 0; c < EMBED; ++c) {
        const float wq = Wq[c * EMBED + e];
        const float wk = Wk[c * EMBED + e];
        const float wv2 = Wv[c * EMBED + e];
        #pragma unroll
        for (int r = 0; r < 8; ++r) {
            const float xc = xn[r][c];
            aq[r] += xc * wq;
            ak[r] += xc * wk;
            av[r] += xc * wv2;
        }
    }
    #pragma unroll
    for (int r = 0; r < 8; ++r) {
        const size_t o = (size_t)(row0 + r) * EMBED + e;
        q[o] = aq[r]; k[o] = ak[r]; v[o] = av[r];
    }
}

// ---- Kernel B: 4 rows/block, fully fused; tail matvecs all float4 ---------
typedef __half scrow_t[HEADS][264];

__global__ __launch_bounds__(256) void scores_pv_ffn_kernel(
    const float* __restrict__ pe,
    const float* __restrict__ mask,
    const float* __restrict__ q, const float* __restrict__ k,
    const float* __restrict__ v,
    const float* __restrict__ x,
    const float* __restrict__ Wo, const float* __restrict__ bo,
    const float* __restrict__ ln2_g, const float* __restrict__ ln2_b,
    const float* __restrict__ W1, const float* __restrict__ b1,
    const float* __restrict__ W2, const float* __restrict__ b2,
    float* __restrict__ out)
{
    const int bid  = blockIdx.x;                    // 0..1023
    const int blk  = (bid & 7) * 128 + (bid >> 3);  // XCD-chunked, bijective
    const int row0 = blk * 4;
    const int bb   = row0 >> 8;
    const int t    = threadIdx.x;                   // 0..255

    __shared__ __align__(16) unsigned char poolA[4 * sizeof(scrow_t)]; // 16.9 KB
    __shared__ __align__(16) unsigned char poolB[4 * NN * 4];          // 4 KB
    __shared__ float red4[4][4][EMBED];    // 8 KB shared reduction buffer
    __shared__ float ctx[4][EMBED];        // 2 KB
    __shared__ float x2s[4][EMBED];        // 2 KB

    scrow_t* sc = reinterpret_cast<scrow_t*>(poolA);            // P1-P3
    float (*hb)[FFN] = reinterpret_cast<float (*)[FFN]>(poolA); // P7+
    float (*msk)[NN] = reinterpret_cast<float (*)[NN]>(poolB);  // P1-P2
    float (*xn2)[EMBED] = reinterpret_cast<float (*)[EMBED]>(poolB); // P6+

    const int g = t >> 5;            // 0..7
    const int l = t & 31;            // lane covers dims 4l..4l+3

    // prefetch mask for 4 rows (rides the stream)
    #pragma unroll
    for (int r = 0; r < 4; ++r)
        msk[r][t] = mask[(size_t)(row0 + r) * NN + t];

    // q fragments for 4 rows
    floatx4 q4[4];
    #pragma unroll
    for (int r = 0; r < 4; ++r)
        q4[r] = *reinterpret_cast<const floatx4*>(q + (size_t)(row0 + r) * EMBED + 4 * l);

    const size_t pe_base = (size_t)row0 * NN * EMBED;
    const size_t k_row   = (size_t)bb * NN * EMBED;
    const int rot = blk & 31;

    // ---- P1: stream pe for 4 rows; k loaded once per j --------------------
    #pragma unroll 4
    for (int jt0 = 0; jt0 < 32; ++jt0) {
        const int jt = (jt0 + rot) & 31;
        const int j  = jt * 8 + g;
        const floatx4 k4 = *reinterpret_cast<const floatx4*>(k + k_row + (size_t)j * EMBED + 4 * l);
        #pragma unroll
        for (int r = 0; r < 4; ++r) {
            const floatx4 p4 = __builtin_nontemporal_load(
                reinterpret_cast<const floatx4*>(pe + pe_base + ((size_t)r * NN + j) * EMBED + 4 * l));
            const floatx4 sum = k4 + p4;
            float s = q4[r].x * sum.x + q4[r].y * sum.y + q4[r].z * sum.z + q4[r].w * sum.w;
            s += __shfl_xor(s, 1);
            s += __shfl_xor(s, 2);
            if ((l & 3) == 0) sc[r][l >> 2][j] = __float2half(s * 0.25f);
        }
    }
    __syncthreads();

    // ---- P2: softmax; group g = head g, loop rows -------------------------
    #pragma unroll
    for (int r = 0; r < 4; ++r) {
        float vals[8];
        float m = -1e30f;
        #pragma unroll
        for (int rr = 0; rr < 8; ++rr) {
            vals[rr] = __half2float(sc[r][g][l + 32 * rr]) + msk[r][l + 32 * rr];
            m = fmaxf(m, vals[rr]);
        }
        #pragma unroll
        for (int off = 16; off >= 1; off >>= 1) m = fmaxf(m, __shfl_xor(m, off));
        float ssum = 0.f;
        #pragma unroll
        for (int rr = 0; rr < 8; ++rr) { float e2 = __expf(vals[rr] - m); vals[rr] = e2; ssum += e2; }
        #pragma unroll
        for (int off = 16; off >= 1; off >>= 1) ssum += __shfl_xor(ssum, off);
        const float inv = 1.0f / ssum;
        #pragma unroll
        for (int rr = 0; rr < 8; ++rr) sc[r][g][l + 32 * rr] = __float2half(vals[rr] * inv);
    }
    __syncthreads();

    // ---- P3: PV. thread (e4, seg): v loaded once, reused x4 rows ----------
    {
        const int e4  = t & 31;
        const int seg = t >> 5;
        const int h   = e4 >> 2;
        floatx4 acc0 = {0,0,0,0}, acc1 = acc0, acc2 = acc0, acc3 = acc0;
        const float* vb = v + ((size_t)(bb * NN + seg * 32)) * EMBED + 4 * e4;
        #pragma unroll 4
        for (int jj = 0; jj < 32; ++jj) {
            const floatx4 v4 = *reinterpret_cast<const floatx4*>(vb + (size_t)jj * EMBED);
            acc0 += __half2float(sc[0][h][seg * 32 + jj]) * v4;
            acc1 += __half2float(sc[1][h][seg * 32 + jj]) * v4;
            acc2 += __half2float(sc[2][h][seg * 32 + jj]) * v4;
            acc3 += __half2float(sc[3][h][seg * 32 + jj]) * v4;
        }
        acc0.x += __shfl_xor(acc0.x, 32); acc0.y += __shfl_xor(acc0.y, 32);
        acc0.z += __shfl_xor(acc0.z, 32); acc0.w += __shfl_xor(acc0.w, 32);
        acc1.x += __shfl_xor(acc1.x, 32); acc1.y += __shfl_xor(acc1.y, 32);
        acc1.z += __shfl_xor(acc1.z, 32); acc1.w += __shfl_xor(acc1.w, 32);
        acc2.x += __shfl_xor(acc2.x, 32); acc2.y += __shfl_xor(acc2.y, 32);
        acc2.z += __shfl_xor(acc2.z, 32); acc2.w += __shfl_xor(acc2.w, 32);
        acc3.x += __shfl_xor(acc3.x, 32); acc3.y += __shfl_xor(acc3.y, 32);
        acc3.z += __shfl_xor(acc3.z, 32); acc3.w += __shfl_xor(acc3.w, 32);
        if ((t & 63) < 32) {
            const int w = t >> 6;
            *reinterpret_cast<floatx4*>(&red4[w][0][4 * e4]) = acc0;
            *reinterpret_cast<floatx4*>(&red4[w][1][4 * e4]) = acc1;
            *reinterpret_cast<floatx4*>(&red4[w][2][4 * e4]) = acc2;
            *reinterpret_cast<floatx4*>(&red4[w][3][4 * e4]) = acc3;
        }
    }
    __syncthreads();
    {
        #pragma unroll
        for (int rr = 0; rr < 2; ++rr) {
            const int idx = t + 256 * rr;      // 0..511 = r*128 + e
            const int r = idx >> 7, e = idx & 127;
            ctx[r][e] = red4[0][r][e] + red4[1][r][e] + red4[2][r][e] + red4[3][r][e];
        }
    }
    __syncthreads();

    // ---- P4: Wo, float4. thread (e4 = t&31, cseg = t>>5): 16 loads --------
    {
        const int e4   = t & 31;
        const int cseg = t >> 5;          // c in [16*cseg, 16*cseg+16)
        floatx4 a0 = {0,0,0,0}, a1 = a0, a2 = a0, a3 = a0;
        const float* Wob = Wo + (size_t)(cseg * 16) * EMBED + 4 * e4;
        #pragma unroll
        for (int cc = 0; cc < 16; ++cc) {
            const floatx4 w4 = *reinterpret_cast<const floatx4*>(Wob + (size_t)cc * EMBED);
            a0 += ctx[0][cseg * 16 + cc] * w4;
            a1 += ctx[1][cseg * 16 + cc] * w4;
            a2 += ctx[2][cseg * 16 + cc] * w4;
            a3 += ctx[3][cseg * 16 + cc] * w4;
        }
        a0.x += __shfl_xor(a0.x, 32); a0.y += __shfl_xor(a0.y, 32);
        a0.z += __shfl_xor(a0.z, 32); a0.w += __shfl_xor(a0.w, 32);
        a1.x += __shfl_xor(a1.x, 32); a1.y += __shfl_xor(a1.y, 32);
        a1.z += __shfl_xor(a1.z, 32); a1.w += __shfl_xor(a1.w, 32);
        a2.x += __shfl_xor(a2.x, 32); a2.y += __shfl_xor(a2.y, 32);
        a2.z += __shfl_xor(a2.z, 32); a2.w += __shfl_xor(a2.w, 32);
        a3.x += __shfl_xor(a3.x, 32); a3.y += __shfl_xor(a3.y, 32);
        a3.z += __shfl_xor(a3.z, 32); a3.w += __shfl_xor(a3.w, 32);
        if ((t & 63) < 32) {
            const int w = t >> 6;
            *reinterpret_cast<floatx4*>(&red4[w][0][4 * e4]) = a0;
            *reinterpret_cast<floatx4*>(&red4[w][1][4 * e4]) = a1;
            *reinterpret_cast<floatx4*>(&red4[w][2][4 * e4]) = a2;
            *reinterpret_cast<floatx4*>(&red4[w][3][4 * e4]) = a3;
        }
    }
    __syncthreads();

    // ---- P5: combine + bias + residual -> x2s ------------------------------
    {
        #pragma unroll
        for (int rr = 0; rr < 2; ++rr) {
            const int idx = t + 256 * rr;
            const int r = idx >> 7, e = idx & 127;
            x2s[r][e] = red4[0][r][e] + red4[1][r][e] + red4[2][r][e] + red4[3][r][e]
                      + bo[e] + x[(size_t)(row0 + r) * EMBED + e];
        }
    }
    __syncthreads();

    // ---- P6: LN2. wave w handles row w; xn2 overlays dead msk -------------
    {
        const int wid = t >> 6, l64 = t & 63;
        const float v0 = x2s[wid][l64], v1 = x2s[wid][l64 + 64];
        float s  = v0 + v1;
        float sq = v0 * v0 + v1 * v1;
        #pragma unroll
        for (int off = 32; off >= 1; off >>= 1) {
            s  += __shfl_xor(s, off);
            sq += __shfl_xor(sq, off);
        }
        const float mu  = s * (1.0f / EMBED);
        const float var = sq * (1.0f / EMBED) - mu * mu;
        const float rs  = rsqrtf(var + 1e-5f);
        xn2[wid][l64]      = (v0 - mu) * rs * ln2_g[l64]      + ln2_b[l64];
        xn2[wid][l64 + 64] = (v1 - mu) * rs * ln2_g[l64 + 64] + ln2_b[l64 + 64];
    }
    __syncthreads();

    // ---- P7: FFN1, float4. thread (f4 = t&127, rp = t>>7): 128 loads ------
    {
        const int f4 = t & 127, rp = t >> 7;
        const int r0 = 2 * rp, r1 = r0 + 1;
        floatx4 h0 = *reinterpret_cast<const floatx4*>(&b1[4 * f4]);
        floatx4 h1 = h0;
        const float* W1b = W1 + 4 * f4;
        #pragma unroll 8
        for (int c = 0; c < EMBED; ++c) {
            const floatx4 w4 = *reinterpret_cast<const floatx4*>(W1b + (size_t)c * FFN);
            h0 += xn2[r0][c] * w4;
            h1 += xn2[r1][c] * w4;
        }
        h0.x = fmaxf(h0.x, 0.f); h0.y = fmaxf(h0.y, 0.f);
        h0.z = fmaxf(h0.z, 0.f); h0.w = fmaxf(h0.w, 0.f);
        h1.x = fmaxf(h1.x, 0.f); h1.y = fmaxf(h1.y, 0.f);
        h1.z = fmaxf(h1.z, 0.f); h1.w = fmaxf(h1.w, 0.f);
        *reinterpret_cast<floatx4*>(&hb[r0][4 * f4]) = h0;
        *reinterpret_cast<floatx4*>(&hb[r1][4 * f4]) = h1;
    }
    __syncthreads();

    // ---- P8: FFN2, float4. thread (e4 = t&31, fseg = t>>5): 64 loads ------
    {
        const int e4   = t & 31;
        const int fseg = t >> 5;          // f in [64*fseg, 64*fseg+64)
        floatx4 a0 = {0,0,0,0}, a1 = a0, a2 = a0, a3 = a0;
        const float* W2b = W2 + (size_t)(fseg * 64) * EMBED + 4 * e4;
        #pragma unroll 4
        for (int ff = 0; ff < 64; ++ff) {
            const floatx4 w4 = *reinterpret_cast<const floatx4*>(W2b + (size_t)ff * EMBED);
            a0 += hb[0][fseg * 64 + ff] * w4;
            a1 += hb[1][fseg * 64 + ff] * w4;
            a2 += hb[2][fseg * 64 + ff] * w4;
            a3 += hb[3][fseg * 64 + ff] * w4;
        }
        a0.x += __shfl_xor(a0.x, 32); a0.y += __shfl_xor(a0.y, 32);
        a0.z += __shfl_xor(a0.z, 32); a0.w += __shfl_xor(a0.w, 32);
        a1.x += __shfl_xor(a1.x, 32); a1.y += __shfl_xor(a1.y, 32);
        a1.z += __shfl_xor(a1.z, 32); a1.w += __shfl_xor(a1.w, 32);
        a2.x += __shfl_xor(a2.x, 32); a2.y += __shfl_xor(a2.y, 32);
        a2.z += __shfl_xor(a2.z, 32); a2.w += __shfl_xor(a2.w, 32);
        a3.x += __shfl_xor(a3.x, 32); a3.y += __shfl_xor(a3.y, 32);
        a3.z += __shfl_xor(a3.z, 32); a3.w += __shfl_xor(a3.w, 32);
        if ((t & 63) < 32) {
            const int w = t >> 6;
            *reinterpret_cast<floatx4*>(&red4[w][0][4 * e4]) = a0;
            *reinterpret_cast<floatx4*>(&red4[w][1][4 * e4]) = a1;
            *reinterpret_cast<floatx4*>(&red4[w][2][4 * e4]) = a2;
            *reinterpret_cast<floatx4*>(&red4[w][3][4 * e4]) = a3;
        }
    }
    __syncthreads();

    // ---- P9: combine + bias + residual -> out ------------------------------
    {
        #pragma unroll
        for (int rr = 0; rr < 2; ++rr) {
            const int idx = t + 256 * rr;
            const int r = idx >> 7, e = idx & 127;
            out[(size_t)(row0 + r) * EMBED + e] =
                x2s[r][e] + b2[e]
                + red4[0][r][e] + red4[1][r][e] + red4[2][r][e] + red4[3][r][e];
        }
    }
}

extern "C" void kernel_launch(void* const* d_in, const int* in_sizes, int n_in,
                              void* d_out, int out_size, void* d_ws, size_t ws_size,
                              hipStream_t stream) {
    const float* x    = (const float*)d_in[0];
    const float* pe   = (const float*)d_in[1];
    const float* mask = (const float*)d_in[2];
    const float* ln1g = (const float*)d_in[3];
    const float* ln1b = (const float*)d_in[4];
    const float* Wq   = (const float*)d_in[5];
    const float* bq   = (const float*)d_in[6];
    const float* Wk   = (const float*)d_in[7];
    const float* bk   = (const float*)d_in[8];
    const float* Wv   = (const float*)d_in[9];
    const float* bv   = (const float*)d_in[10];
    const float* Wo   = (const float*)d_in[11];
    const float* bo   = (const float*)d_in[12];
    const float* ln2g = (const float*)d_in[13];
    const float* ln2b = (const float*)d_in[14];
    const float* W1   = (const float*)d_in[15];
    const float* b1   = (const float*)d_in[16];
    const float* W2   = (const float*)d_in[17];
    const float* b2   = (const float*)d_in[18];
    float* out = (float*)d_out;

    float* q  = (float*)d_ws;
    float* kk = q  + (size_t)BB * NN * EMBED;
    float* vv = kk + (size_t)BB * NN * EMBED;

    ln1_qkv_kernel<<<BB * NN / 8, 128, 0, stream>>>(x, ln1g, ln1b, Wq, bq, Wk, bk, Wv, bv, q, kk, vv);
    scores_pv_ffn_kernel<<<BB * NN / 4, 256, 0, stream>>>(pe, mask, q, kk, vv, x,
                                                          Wo, bo, ln2g, ln2b,
                                                          W1, b1, W2, b2, out);
}

// Round 16
// 152.776 us; speedup vs baseline: 1.4078x; 1.4078x over previous
//
#include <hip/hip_runtime.h>
#include <hip/hip_bf16.h>
#include <hip/hip_fp16.h>

#define EMBED 128
#define HEADS 8
#define DH 16
#define FFN 512
#define BB 16
#define NN 256

typedef float floatx4 __attribute__((ext_vector_type(4)));

// ---- Kernel A: LN1 + QKV, 8 rows/block (weights read once per 8 rows) -----
__global__ __launch_bounds__(128) void ln1_qkv_kernel(
    const float* __restrict__ x,
    const float* __restrict__ ln1_g, const float* __restrict__ ln1_b,
    const float* __restrict__ Wq, const float* __restrict__ bq,
    const float* __restrict__ Wk, const float* __restrict__ bk,
    const float* __restrict__ Wv, const float* __restrict__ bv,
    float* __restrict__ q, float* __restrict__ k, float* __restrict__ v)
{
    const int row0 = blockIdx.x * 8;     // 512 blocks
    const int t    = threadIdx.x;        // 0..127
    const int wv_  = t >> 6;             // wave 0..1
    const int l64  = t & 63;

    __shared__ float xn[8][EMBED];

    #pragma unroll
    for (int rr = 0; rr < 4; ++rr) {
        const int r = wv_ * 4 + rr;
        const float v0 = x[(size_t)(row0 + r) * EMBED + l64];
        const float v1 = x[(size_t)(row0 + r) * EMBED + 64 + l64];
        float s  = v0 + v1;
        float sq = v0 * v0 + v1 * v1;
        #pragma unroll
        for (int off = 32; off >= 1; off >>= 1) {
            s  += __shfl_xor(s, off);
            sq += __shfl_xor(sq, off);
        }
        const float mu  = s * (1.0f / EMBED);
        const float var = sq * (1.0f / EMBED) - mu * mu;
        const float rs  = rsqrtf(var + 1e-5f);
        xn[r][l64]      = (v0 - mu) * rs * ln1_g[l64]      + ln1_b[l64];
        xn[r][l64 + 64] = (v1 - mu) * rs * ln1_g[l64 + 64] + ln1_b[l64 + 64];
    }
    __syncthreads();

    const int e = t;
    float aq[8], ak[8], av[8];
    const float bqe = bq[e], bke = bk[e], bve = bv[e];
    #pragma unroll
    for (int r = 0; r < 8; ++r) { aq[r] = bqe; ak[r] = bke; av[r] = bve; }

    #pragma unroll 4
    for (int c = 0; c < EMBED; ++c) {
        const float wq = Wq[c * EMBED + e];
        const float wk = Wk[c * EMBED + e];
        const float wv2 = Wv[c * EMBED + e];
        #pragma unroll
        for (int r = 0; r < 8; ++r) {
            const float xc = xn[r][c];
            aq[r] += xc * wq;
            ak[r] += xc * wk;
            av[r] += xc * wv2;
        }
    }
    #pragma unroll
    for (int r = 0; r < 8; ++r) {
        const size_t o = (size_t)(row0 + r) * EMBED + e;
        q[o] = aq[r]; k[o] = ak[r]; v[o] = av[r];
    }
}

// ---- Kernel B: 4 rows/block, fully fused (R14 structure), VGPR-capped -----
// __launch_bounds__(256, 4): 4 waves/EU => 4 blocks/CU => VGPR cap 128.
typedef __half scrow_t[HEADS][264];

__global__ __launch_bounds__(256, 4) void scores_pv_ffn_kernel(
    const float* __restrict__ pe,
    const float* __restrict__ mask,
    const float* __restrict__ q, const float* __restrict__ k,
    const float* __restrict__ v,
    const float* __restrict__ x,
    const float* __restrict__ Wo, const float* __restrict__ bo,
    const float* __restrict__ ln2_g, const float* __restrict__ ln2_b,
    const float* __restrict__ W1, const float* __restrict__ b1,
    const float* __restrict__ W2, const float* __restrict__ b2,
    float* __restrict__ out)
{
    const int bid  = blockIdx.x;                    // 0..1023
    const int blk  = (bid & 7) * 128 + (bid >> 3);  // XCD-chunked, bijective
    const int row0 = blk * 4;
    const int bb   = row0 >> 8;
    const int t    = threadIdx.x;                   // 0..255

    __shared__ __align__(16) unsigned char poolA[4 * sizeof(scrow_t)]; // 16.9 KB
    __shared__ __align__(16) unsigned char poolB[4 * NN * 4];          // 4 KB
    __shared__ float red4[4][4][EMBED];    // 8 KB PV wave partials
    __shared__ float ctx[4][EMBED];        // 2 KB
    __shared__ float wred[2][4][EMBED];    // 4 KB Wo / FFN2 partials
    __shared__ float x2s[4][EMBED];        // 2 KB

    scrow_t* sc = reinterpret_cast<scrow_t*>(poolA);            // phases 1-3
    float (*hb)[FFN] = reinterpret_cast<float (*)[FFN]>(poolA); // phase FFN1+
    float (*msk)[NN] = reinterpret_cast<float (*)[NN]>(poolB);  // phases 1-2
    float (*xn2)[EMBED] = reinterpret_cast<float (*)[EMBED]>(poolB); // P6+

    const int g = t >> 5;            // 0..7
    const int l = t & 31;            // lane covers dims 4l..4l+3

    // prefetch mask for 4 rows (rides the stream)
    #pragma unroll
    for (int r = 0; r < 4; ++r)
        msk[r][t] = mask[(size_t)(row0 + r) * NN + t];

    // q fragments for 4 rows
    floatx4 q4[4];
    #pragma unroll
    for (int r = 0; r < 4; ++r)
        q4[r] = *reinterpret_cast<const floatx4*>(q + (size_t)(row0 + r) * EMBED + 4 * l);

    const size_t pe_base = (size_t)row0 * NN * EMBED;
    const size_t k_row   = (size_t)bb * NN * EMBED;
    const int rot = blk & 31;

    // ---- P1: stream pe for 4 rows; k loaded once per j --------------------
    #pragma unroll 4
    for (int jt0 = 0; jt0 < 32; ++jt0) {
        const int jt = (jt0 + rot) & 31;
        const int j  = jt * 8 + g;
        const floatx4 k4 = *reinterpret_cast<const floatx4*>(k + k_row + (size_t)j * EMBED + 4 * l);
        #pragma unroll
        for (int r = 0; r < 4; ++r) {
            const floatx4 p4 = __builtin_nontemporal_load(
                reinterpret_cast<const floatx4*>(pe + pe_base + ((size_t)r * NN + j) * EMBED + 4 * l));
            const floatx4 sum = k4 + p4;
            float s = q4[r].x * sum.x + q4[r].y * sum.y + q4[r].z * sum.z + q4[r].w * sum.w;
            s += __shfl_xor(s, 1);
            s += __shfl_xor(s, 2);
            if ((l & 3) == 0) sc[r][l >> 2][j] = __float2half(s * 0.25f);
        }
    }
    __syncthreads();

    // ---- P2: softmax; group g = head g, loop rows -------------------------
    #pragma unroll
    for (int r = 0; r < 4; ++r) {
        float vals[8];
        float m = -1e30f;
        #pragma unroll
        for (int rr = 0; rr < 8; ++rr) {
            vals[rr] = __half2float(sc[r][g][l + 32 * rr]) + msk[r][l + 32 * rr];
            m = fmaxf(m, vals[rr]);
        }
        #pragma unroll
        for (int off = 16; off >= 1; off >>= 1) m = fmaxf(m, __shfl_xor(m, off));
        float ssum = 0.f;
        #pragma unroll
        for (int rr = 0; rr < 8; ++rr) { float e2 = __expf(vals[rr] - m); vals[rr] = e2; ssum += e2; }
        #pragma unroll
        for (int off = 16; off >= 1; off >>= 1) ssum += __shfl_xor(ssum, off);
        const float inv = 1.0f / ssum;
        #pragma unroll
        for (int rr = 0; rr < 8; ++rr) sc[r][g][l + 32 * rr] = __float2half(vals[rr] * inv);
    }
    __syncthreads();

    // ---- P3: PV. thread (e4, seg): v loaded once, reused x4 rows ----------
    {
        const int e4  = t & 31;
        const int seg = t >> 5;
        const int h   = e4 >> 2;
        floatx4 acc0 = {0,0,0,0}, acc1 = acc0, acc2 = acc0, acc3 = acc0;
        const float* vb = v + ((size_t)(bb * NN + seg * 32)) * EMBED + 4 * e4;
        #pragma unroll 4
        for (int jj = 0; jj < 32; ++jj) {
            const floatx4 v4 = *reinterpret_cast<const floatx4*>(vb + (size_t)jj * EMBED);
            acc0 += __half2float(sc[0][h][seg * 32 + jj]) * v4;
            acc1 += __half2float(sc[1][h][seg * 32 + jj]) * v4;
            acc2 += __half2float(sc[2][h][seg * 32 + jj]) * v4;
            acc3 += __half2float(sc[3][h][seg * 32 + jj]) * v4;
        }
        acc0.x += __shfl_xor(acc0.x, 32); acc0.y += __shfl_xor(acc0.y, 32);
        acc0.z += __shfl_xor(acc0.z, 32); acc0.w += __shfl_xor(acc0.w, 32);
        acc1.x += __shfl_xor(acc1.x, 32); acc1.y += __shfl_xor(acc1.y, 32);
        acc1.z += __shfl_xor(acc1.z, 32); acc1.w += __shfl_xor(acc1.w, 32);
        acc2.x += __shfl_xor(acc2.x, 32); acc2.y += __shfl_xor(acc2.y, 32);
        acc2.z += __shfl_xor(acc2.z, 32); acc2.w += __shfl_xor(acc2.w, 32);
        acc3.x += __shfl_xor(acc3.x, 32); acc3.y += __shfl_xor(acc3.y, 32);
        acc3.z += __shfl_xor(acc3.z, 32); acc3.w += __shfl_xor(acc3.w, 32);
        if ((t & 63) < 32) {
            const int w = t >> 6;
            *reinterpret_cast<floatx4*>(&red4[w][0][4 * e4]) = acc0;
            *reinterpret_cast<floatx4*>(&red4[w][1][4 * e4]) = acc1;
            *reinterpret_cast<floatx4*>(&red4[w][2][4 * e4]) = acc2;
            *reinterpret_cast<floatx4*>(&red4[w][3][4 * e4]) = acc3;
        }
    }
    __syncthreads();
    {
        #pragma unroll
        for (int rr = 0; rr < 2; ++rr) {
            const int idx = t + 256 * rr;      // 0..511 = r*128 + e
            const int r = idx >> 7, e = idx & 127;
            ctx[r][e] = red4[0][r][e] + red4[1][r][e] + red4[2][r][e] + red4[3][r][e];
        }
    }
    __syncthreads();

    // ---- P4: Wo. thread (e, rp = c-half); Wo element reused x4 rows -------
    {
        const int e = t & 127, rp = t >> 7;
        float a0 = 0.f, a1 = 0.f, a2 = 0.f, a3 = 0.f;
        const float* Wob = Wo + rp * 64 * EMBED + e;
        #pragma unroll 8
        for (int cc = 0; cc < 64; ++cc) {
            const float w = Wob[(size_t)cc * EMBED];
            a0 += ctx[0][rp * 64 + cc] * w;
            a1 += ctx[1][rp * 64 + cc] * w;
            a2 += ctx[2][rp * 64 + cc] * w;
            a3 += ctx[3][rp * 64 + cc] * w;
        }
        wred[rp][0][e] = a0; wred[rp][1][e] = a1;
        wred[rp][2][e] = a2; wred[rp][3][e] = a3;
    }
    __syncthreads();

    // ---- P5: combine + bias + residual -> x2s ------------------------------
    {
        #pragma unroll
        for (int rr = 0; rr < 2; ++rr) {
            const int idx = t + 256 * rr;
            const int r = idx >> 7, e = idx & 127;
            x2s[r][e] = wred[0][r][e] + wred[1][r][e] + bo[e]
                      + x[(size_t)(row0 + r) * EMBED + e];
        }
    }
    __syncthreads();

    // ---- P6: LN2. wave w handles row w; xn2 overlays dead msk -------------
    {
        const int wid = t >> 6, l64 = t & 63;
        const float v0 = x2s[wid][l64], v1 = x2s[wid][l64 + 64];
        float s  = v0 + v1;
        float sq = v0 * v0 + v1 * v1;
        #pragma unroll
        for (int off = 32; off >= 1; off >>= 1) {
            s  += __shfl_xor(s, off);
            sq += __shfl_xor(sq, off);
        }
        const float mu  = s * (1.0f / EMBED);
        const float var = sq * (1.0f / EMBED) - mu * mu;
        const float rs  = rsqrtf(var + 1e-5f);
        xn2[wid][l64]      = (v0 - mu) * rs * ln2_g[l64]      + ln2_b[l64];
        xn2[wid][l64 + 64] = (v1 - mu) * rs * ln2_g[l64 + 64] + ln2_b[l64 + 64];
    }
    __syncthreads();

    // ---- P7: FFN1. thread t -> hidden cols {t, t+256}; hb overlays sc -----
    {
        float h0[4], h1[4];
        const float c0 = b1[t], c1 = b1[t + 256];
        #pragma unroll
        for (int r = 0; r < 4; ++r) { h0[r] = c0; h1[r] = c1; }
        #pragma unroll 4
        for (int c = 0; c < EMBED; ++c) {
            const float w0 = W1[c * FFN + t];
            const float w1 = W1[c * FFN + t + 256];
            #pragma unroll
            for (int r = 0; r < 4; ++r) {
                const float xc = xn2[r][c];
                h0[r] += xc * w0;
                h1[r] += xc * w1;
            }
        }
        #pragma unroll
        for (int r = 0; r < 4; ++r) {
            hb[r][t]       = fmaxf(h0[r], 0.f);
            hb[r][t + 256] = fmaxf(h1[r], 0.f);
        }
    }
    __syncthreads();

    // ---- P8: FFN2. thread (e, rp = f-half); wred reused for partials ------
    {
        const int e = t & 127, rp = t >> 7;
        float a0 = 0.f, a1 = 0.f, a2 = 0.f, a3 = 0.f;
        const float* W2b = W2 + (size_t)(rp * 256) * EMBED + e;
        #pragma unroll 8
        for (int ff = 0; ff < 256; ++ff) {
            const float w = W2b[(size_t)ff * EMBED];
            a0 += hb[0][rp * 256 + ff] * w;
            a1 += hb[1][rp * 256 + ff] * w;
            a2 += hb[2][rp * 256 + ff] * w;
            a3 += hb[3][rp * 256 + ff] * w;
        }
        wred[rp][0][e] = a0; wred[rp][1][e] = a1;
        wred[rp][2][e] = a2; wred[rp][3][e] = a3;
    }
    __syncthreads();

    // ---- P9: combine + bias + residual -> out ------------------------------
    {
        #pragma unroll
        for (int rr = 0; rr < 2; ++rr) {
            const int idx = t + 256 * rr;
            const int r = idx >> 7, e = idx & 127;
            out[(size_t)(row0 + r) * EMBED + e] =
                x2s[r][e] + b2[e] + wred[0][r][e] + wred[1][r][e];
        }
    }
}

extern "C" void kernel_launch(void* const* d_in, const int* in_sizes, int n_in,
                              void* d_out, int out_size, void* d_ws, size_t ws_size,
                              hipStream_t stream) {
    const float* x    = (const float*)d_in[0];
    const float* pe   = (const float*)d_in[1];
    const float* mask = (const float*)d_in[2];
    const float* ln1g = (const float*)d_in[3];
    const float* ln1b = (const float*)d_in[4];
    const float* Wq   = (const float*)d_in[5];
    const float* bq   = (const float*)d_in[6];
    const float* Wk   = (const float*)d_in[7];
    const float* bk   = (const float*)d_in[8];
    const float* Wv   = (const float*)d_in[9];
    const float* bv   = (const float*)d_in[10];
    const float* Wo   = (const float*)d_in[11];
    const float* bo   = (const float*)d_in[12];
    const float* ln2g = (const float*)d_in[13];
    const float* ln2b = (const float*)d_in[14];
    const float* W1   = (const float*)d_in[15];
    const float* b1   = (const float*)d_in[16];
    const float* W2   = (const float*)d_in[17];
    const float* b2   = (const float*)d_in[18];
    float* out = (float*)d_out;

    float* q  = (float*)d_ws;
    float* kk = q  + (size_t)BB * NN * EMBED;
    float* vv = kk + (size_t)BB * NN * EMBED;

    ln1_qkv_kernel<<<BB * NN / 8, 128, 0, stream>>>(x, ln1g, ln1b, Wq, bq, Wk, bk, Wv, bv, q, kk, vv);
    scores_pv_ffn_kernel<<<BB * NN / 4, 256, 0, stream>>>(pe, mask, q, kk, vv, x,
                                                          Wo, bo, ln2g, ln2b,
                                                          W1, b1, W2, b2, out);
}